// Round 5
// baseline (260.468 us; speedup 1.0000x reference)
//
#include <hip/hip_runtime.h>

// x: (1,3,128,128) fp32 | w,q: (3,124,124,25,5,5) fp32 | out: (1,3,124,124,25) fp32
// out[o] = sum_{k=0..24} log(1.1 + atan(10*(x_k*w_k - q_k))/pi)
//
// R5: element-order streaming with continuous prefetch (no drain-then-compute).
// R1-R4 post-mortem: all four structures sustained ~2.5 TB/s because loads were
// batched then fully drained before compute (in-flight duty cycle ~5 KB/CU;
// Little's law -> 2.5 TB/s). Here each thread computes log-terms directly on
// its own loaded float4s (x gathered per-element via magic-div decode; x is
// L1/L2-resident), so chunk c+1's loads stay in flight through chunk c's
// compute. Wave-private LDS does only the tiny 25-way segmented sum; NO
// __syncthreads anywhere.

#define IMG    128
#define OUTD   124
#define NUM    25
#define NOUT   (3 * OUTD * OUTD * NUM)   // 1,153,200
#define WTOT   28830000u                  // NOUT*25 (fits uint32)
#define CHUNK  1600u                      // 64 outputs per wave-chunk
#define NCHUNK 18019u                     // ceil(WTOT/CHUNK); last chunk has 1200
#define WPB    4
#define OPB    (WPB * 64)
#define CPW    3                          // chunks per wave
#define NBLK   1504                       // 6016 waves * 3 >= 18019 chunks

// Minimax atan, |err| ~ 2e-6. Range-reduce with v_rcp_f32.
__device__ __forceinline__ float fast_atan(float z) {
    float az  = __builtin_fabsf(z);
    float r   = __builtin_amdgcn_rcpf(az);
    bool  big = az > 1.0f;
    float t   = big ? r : az;
    float s   = t * t;
    float p   =                     -0.01172120f;
    p = __builtin_fmaf(p, s,         0.05265332f);
    p = __builtin_fmaf(p, s,        -0.11643287f);
    p = __builtin_fmaf(p, s,         0.19354346f);
    p = __builtin_fmaf(p, s,        -0.33262347f);
    p = __builtin_fmaf(p, s,         0.99997726f);
    float a = t * p;
    a = big ? (1.57079632679489662f - a) : a;
    return __builtin_copysignf(a, z);
}

// Per-element log-term. e is the flat element index into w/q.
// Decode e -> (c,i,j,u,v) with compile-time-constant divisors (magic mul).
__device__ __forceinline__ float log_term(const float* __restrict__ x,
                                          unsigned e, float wv, float qv) {
    const unsigned ee = e < (WTOT - 1u) ? e : (WTOT - 1u);  // clamp for decode/x
    const unsigned v  = ee % 5u;
    const unsigned u  = (ee / 5u) % 5u;
    const unsigned m  = ee / 625u;            // = output_spatial = (c*124+i)*124+j
    const unsigned j  = m % 124u;
    const unsigned t  = m / 124u;
    const unsigned i_ = t % 124u;
    const unsigned ci = t / 124u;
    const float xv = x[ci * (IMG * IMG) + (i_ + u) * IMG + (j + v)];
    const float z  = 10.0f * __builtin_fmaf(xv, wv, -qv);
    const float a  = fast_atan(z);
    const float term = __builtin_fmaf(a, 0.31830988618379067f, 1.1f);
    const float lt = __logf(term);
    return e < WTOT ? lt : 0.0f;              // pad elements contribute 0
}

// Coalesced chunk load: 6 aligned dwordx4 + 1 dword per array, per thread.
__device__ __forceinline__ void load_chunk(unsigned c,
    const float* __restrict__ w, const float* __restrict__ q, int lane,
    float4 W[6], float4 Q[6], float& Wt, float& Qt) {
    const unsigned base = c * CHUNK;
    #pragma unroll
    for (int i = 0; i < 6; ++i) {
        unsigned gi = base + 256u * i + 4u * lane;
        if (gi > WTOT - 4u) gi = WTOT - 4u;   // stays 16B-aligned (WTOT%4==0)
        W[i] = *(const float4*)(w + gi);
        Q[i] = *(const float4*)(q + gi);
    }
    unsigned gt = base + 1536u + lane;
    if (gt > WTOT - 1u) gt = WTOT - 1u;
    Wt = w[gt];
    Qt = q[gt];
}

__global__ __launch_bounds__(OPB, 3) void dendrite_kernel(
    const float* __restrict__ x,
    const float* __restrict__ w,
    const float* __restrict__ q,
    float* __restrict__ out)
{
    __shared__ float lds[WPB][CHUNK];        // 25,600 B/block; wave-private slices

    const int lane = threadIdx.x & 63;
    const int wib  = threadIdx.x >> 6;
    const unsigned wgid = blockIdx.x * WPB + wib;
    const unsigned c0   = wgid * CPW;
    if (c0 >= NCHUNK) return;                // wave-uniform

    float4 W[6], Q[6]; float Wt, Qt;
    load_chunk(c0, w, q, lane, W, Q, Wt, Qt);

    #pragma unroll
    for (int s = 0; s < CPW; ++s) {
        const unsigned c = c0 + s;
        if (c >= NCHUNK) break;

        // ---- Prefetch next chunk: 14 loads in flight through this compute ----
        float4 Wn[6], Qn[6]; float Wtn = 0.0f, Qtn = 0.0f;
        const bool pf = (s + 1 < CPW) && (c + 1 < NCHUNK);
        if (pf) load_chunk(c + 1, w, q, lane, Wn, Qn, Wtn, Qtn);

        // ---- Compute current chunk in element order ----
        const unsigned base = c * CHUNK;
        #pragma unroll
        for (int i = 0; i < 6; ++i) {
            const unsigned el0 = 256u * i + 4u * lane;
            const float* wf = (const float*)&W[i];
            const float* qf = (const float*)&Q[i];
            float lt[4];
            #pragma unroll
            for (int jj = 0; jj < 4; ++jj)
                lt[jj] = log_term(x, base + el0 + jj, wf[jj], qf[jj]);
            *(float4*)&lds[wib][el0] = make_float4(lt[0], lt[1], lt[2], lt[3]);
        }
        lds[wib][1536u + lane] = log_term(x, base + 1536u + lane, Wt, Qt);

        // Wave-internal visibility only (wave64 lockstep, DS ops in order):
        __asm volatile("s_waitcnt lgkmcnt(0)" ::: "memory");

        // ---- 25-way segmented sum; stride 25 (odd) -> 2 lanes/bank, free ----
        float sum = 0.0f;
        #pragma unroll
        for (int k = 0; k < NUM; ++k)
            sum += lds[wib][lane * NUM + k];

        const unsigned o = c * 64u + lane;
        if (o < (unsigned)NOUT) out[o] = sum;

        __asm volatile("" ::: "memory");     // keep next writes after these reads

        if (pf) {
            #pragma unroll
            for (int i = 0; i < 6; ++i) { W[i] = Wn[i]; Q[i] = Qn[i]; }
            Wt = Wtn; Qt = Qtn;
        }
    }
}

extern "C" void kernel_launch(void* const* d_in, const int* in_sizes, int n_in,
                              void* d_out, int out_size, void* d_ws, size_t ws_size,
                              hipStream_t stream) {
    const float* x = (const float*)d_in[0];
    const float* w = (const float*)d_in[1];
    const float* q = (const float*)d_in[2];
    float* out = (float*)d_out;

    dendrite_kernel<<<NBLK, OPB, 0, stream>>>(x, w, q, out);
}

// Round 6
// 251.523 us; speedup vs baseline: 1.0356x; 1.0356x over previous
//
#include <hip/hip_runtime.h>

// x: (1,3,128,128) fp32 | w,q: (3,124,124,25,5,5) fp32 | out: (1,3,124,124,25) fp32
// out[o] = log( prod_{k=0..24} (1.1 + atan(10*(x_k*w_k - q_k))/pi) )
//
// R6: persistent waves, rolling register->LDS pipeline.
// R1-R5 lesson: every prior structure drained ALL loads before compute (0 bytes
// in flight during the 1400-cyc compute phase) -> ~2.4 TB/s. R5's element-order
// decode was VALU-poisoned (112 ops/elem) and its prefetch was compiler-sunk
// (VGPR=76). Here: thread=output (light VALU), each wave runs 6 chunks; chunk
// k+1's 14 global loads are issued AFTER chunk k's x loads and stay in flight
// through chunk k's compute (compute reads w/q from LDS -> lgkmcnt only; x-use
// waits vmcnt(14), not 0). No __syncthreads; LDS slices are wave-private.

#define IMG    128
#define OUTD   124
#define NUM    25
#define NOUT   1153200
#define WTOT   28830000u
#define NCHUNK 18019u
#define WPB    4
#define OPB    256
#define NBLK   768        // 3072 waves = exactly 3 blocks/CU, persistent
#define NWAVE  3072u
#define ITERS  6          // 3072*6 = 18432 >= 18019 (tail waves dup chunk 18018)

// Minimax atan, |err| ~ 2e-6. Range-reduce with v_rcp_f32.
__device__ __forceinline__ float fast_atan(float z) {
    float az  = __builtin_fabsf(z);
    float r   = __builtin_amdgcn_rcpf(az);
    bool  big = az > 1.0f;
    float t   = big ? r : az;
    float s   = t * t;
    float p   =                     -0.01172120f;
    p = __builtin_fmaf(p, s,         0.05265332f);
    p = __builtin_fmaf(p, s,        -0.11643287f);
    p = __builtin_fmaf(p, s,         0.19354346f);
    p = __builtin_fmaf(p, s,        -0.33262347f);
    p = __builtin_fmaf(p, s,         0.99997726f);
    float a = t * p;
    a = big ? (1.57079632679489662f - a) : a;
    return __builtin_copysignf(a, z);
}

struct ChunkRegs { float4 W[6]; float4 Q[6]; float Wt, Qt; };  // 56 VGPRs

// Coalesced chunk load (1600 floats per array): 6 aligned dwordx4 + 1 dword
// per lane. Clamps keep the dup/tail chunk in bounds (garbage values are
// harmless: atan is bounded, stores are guarded).
__device__ __forceinline__ void load_chunk(unsigned ch,
    const float* __restrict__ w, const float* __restrict__ q, int lane,
    ChunkRegs& r) {
    const unsigned base = ch * 1600u;
    #pragma unroll
    for (int it = 0; it < 6; ++it) {
        unsigned gi = base + 256u * it + 4u * lane;
        gi = gi > WTOT - 4u ? WTOT - 4u : gi;     // stays 16B-aligned
        r.W[it] = *(const float4*)(w + gi);
        r.Q[it] = *(const float4*)(q + gi);
    }
    unsigned gt = base + 1536u + lane;
    gt = gt > WTOT - 1u ? WTOT - 1u : gt;
    r.Wt = w[gt];
    r.Qt = q[gt];
}

__global__ __launch_bounds__(OPB, 3) void dendrite_kernel(
    const float* __restrict__ x,
    const float* __restrict__ w,
    const float* __restrict__ q,
    float* __restrict__ out)
{
    __shared__ float lw[WPB][1600];   // 25,600 B
    __shared__ float lq[WPB][1600];   // 25,600 B -> 51,200 B/block, 3 blk/CU

    const int lane = threadIdx.x & 63;
    const int wv   = threadIdx.x >> 6;
    const unsigned g = blockIdx.x * WPB + wv;     // wave id, 0..3071

    ChunkRegs cur;
    load_chunk(g, w, q, lane, cur);               // prologue: chunk for s=0

    #pragma unroll
    for (int s = 0; s < ITERS; ++s) {
        unsigned ch = g + (unsigned)s * NWAVE;
        ch = ch < NCHUNK ? ch : NCHUNK - 1u;      // dup chunk: identical values

        // -- 1. Stage current chunk regs -> wave-private LDS.
        //    vmcnt wait here is shallow (only last iter's out-store is newer).
        #pragma unroll
        for (int it = 0; it < 6; ++it) {
            *(float4*)&lw[wv][256 * it + 4 * lane] = cur.W[it];
            *(float4*)&lq[wv][256 * it + 4 * lane] = cur.Q[it];
        }
        lw[wv][1536 + lane] = cur.Wt;
        lq[wv][1536 + lane] = cur.Qt;

        // -- 2. x patch loads for THIS chunk (issued BEFORE the prefetch so the
        //    compiler's x-wait never drains the prefetch).
        const int o  = (int)(ch * 64u) + lane;
        const int oc = o < NOUT ? o : NOUT - 1;
        const int m  = oc / NUM;
        const int j  = m % OUTD;
        const int t2 = m / OUTD;
        const int i  = t2 % OUTD;
        const int cc = t2 / OUTD;
        const float* xp = x + (cc * IMG + i) * IMG + j;
        float xv[NUM];
        #pragma unroll
        for (int u = 0; u < 5; ++u) {
            float4 a;
            __builtin_memcpy(&a, xp + u * IMG, sizeof(float4));  // L1-hot broadcast
            xv[5*u+0] = a.x; xv[5*u+1] = a.y; xv[5*u+2] = a.z; xv[5*u+3] = a.w;
            xv[5*u+4] = xp[u * IMG + 4];
        }

        // -- 3. Prefetch next chunk into the just-freed regs: these 14 loads
        //    stay in flight through the entire compute below.
        if (s + 1 < ITERS) {
            unsigned chn = g + (unsigned)(s + 1) * NWAVE;
            chn = chn < NCHUNK ? chn : NCHUNK - 1u;
            load_chunk(chn, w, q, lane, cur);
        }

        // -- 4. Compute: w/q fragments straight from LDS (lgkmcnt-only waits;
        //    wave64 lockstep makes the write->read ordering safe, no barrier).
        const float* wp = &lw[wv][lane * NUM];    // stride 25: 2 lanes/bank, free
        const float* qp = &lq[wv][lane * NUM];
        float prod0 = 1.0f, prod1 = 1.0f;
        #pragma unroll
        for (int k = 0; k < NUM; ++k) {
            const float z = 10.0f * __builtin_fmaf(xv[k], wp[k], -qp[k]);
            const float a = fast_atan(z);
            const float term = __builtin_fmaf(a, 0.31830988618379067f, 1.1f);
            if (k & 1) prod1 *= term; else prod0 *= term;
        }
        if (o < NOUT) out[o] = __logf(prod0 * prod1);
    }
}

extern "C" void kernel_launch(void* const* d_in, const int* in_sizes, int n_in,
                              void* d_out, int out_size, void* d_ws, size_t ws_size,
                              hipStream_t stream) {
    const float* x = (const float*)d_in[0];
    const float* w = (const float*)d_in[1];
    const float* q = (const float*)d_in[2];
    float* out = (float*)d_out;

    dendrite_kernel<<<NBLK, OPB, 0, stream>>>(x, w, q, out);
}